// Round 14
// baseline (2813.175 us; speedup 1.0000x reference)
//
#include <hip/hip_runtime.h>
#include <stdint.h>
#include <math.h>

// Replicate jax.random threefry2x32 exactly (jax_threefry_partitionable=True).
#define PARTITIONABLE 1

namespace {

constexpr int kB = 4096;
constexpr int kN = 256;
constexpr int kSweeps = 200;
constexpr int kSamp = 16;                // samples per block
constexpr int kBlocks = kB / kSamp;      // 256 blocks of 512 threads -> 1/CU
// Merge of r12 + r13:
//  waves 0-3: wave-private annealers (r12) — each owns 4 samples completely;
//    lane holds rows 4l..4l+3 (spins = 2 VGPR/sample, fp16-packed); spin
//    broadcast via v_readlane -> SGPR -> v_fma_mix scalar operand; J loads
//    are contiguous 1KB wave reads. NO spin LDS (the measured ~24cyc/
//    broadcast-b128 wall, 1024 reads/CU/sweep in r13, goes to zero).
//  waves 4-7: producers (r13) — next sweep's threefry into LDS rand dbuf,
//    conflict-free 16B/lane stores. Wave w -> SIMD w%4: every SIMD runs
//    1 consumer + 1 producer; producer VALU hides consumer load latency.

struct K2 { uint32_t a, b; };

__host__ __device__ constexpr uint32_t crotl(uint32_t x, int d) {
  return (x << d) | (x >> (32 - d));
}

// Threefry-2x32, 20 rounds, exactly as jax/_src/prng.py
__host__ __device__ constexpr K2 ctf(uint32_t k0, uint32_t k1, uint32_t c0, uint32_t c1) {
  uint32_t ks0 = k0, ks1 = k1, ks2 = k0 ^ k1 ^ 0x1BD11BDAu;
  uint32_t x0 = c0 + ks0, x1 = c1 + ks1;
  const int r0[4] = {13, 15, 26, 6};
  const int r1[4] = {17, 29, 16, 24};
  for (int i = 0; i < 4; ++i) { x0 += x1; x1 = crotl(x1, r0[i]); x1 ^= x0; }
  x0 += ks1; x1 += ks2 + 1u;
  for (int i = 0; i < 4; ++i) { x0 += x1; x1 = crotl(x1, r1[i]); x1 ^= x0; }
  x0 += ks2; x1 += ks0 + 2u;
  for (int i = 0; i < 4; ++i) { x0 += x1; x1 = crotl(x1, r0[i]); x1 ^= x0; }
  x0 += ks0; x1 += ks1 + 3u;
  for (int i = 0; i < 4; ++i) { x0 += x1; x1 = crotl(x1, r1[i]); x1 ^= x0; }
  x0 += ks1; x1 += ks2 + 4u;
  for (int i = 0; i < 4; ++i) { x0 += x1; x1 = crotl(x1, r0[i]); x1 ^= x0; }
  x0 += ks2; x1 += ks0 + 5u;
  return K2{x0, x1};
}

struct KeyTable {
  uint32_t s0k[2];               // key for initial spins (k0)
  uint32_t sk[kSweeps][4];       // per sweep: k1a,k1b (accept), k2a,k2b (mask)
};

constexpr KeyTable make_keys() {
  KeyTable t{};
  K2 root{0u, 42u};              // jax.random.key(42) -> (hi=0, lo=42)
#if PARTITIONABLE
  K2 k0 = ctf(root.a, root.b, 0u, 0u);
  K2 kl = ctf(root.a, root.b, 0u, 1u);
#else
  K2 p0 = ctf(root.a, root.b, 0u, 2u);
  K2 p1 = ctf(root.a, root.b, 1u, 3u);
  K2 k0{p0.a, p1.a};
  K2 kl{p0.b, p1.b};
#endif
  t.s0k[0] = k0.a; t.s0k[1] = k0.b;
  K2 k = kl;
  for (int s = 0; s < kSweeps; ++s) {
#if PARTITIONABLE
    K2 kn = ctf(k.a, k.b, 0u, 0u);
    K2 k1 = ctf(k.a, k.b, 0u, 1u);
    K2 k2 = ctf(k.a, k.b, 0u, 2u);
#else
    K2 q0 = ctf(k.a, k.b, 0u, 3u);
    K2 q1 = ctf(k.a, k.b, 1u, 4u);
    K2 q2 = ctf(k.a, k.b, 2u, 5u);
    K2 kn{q0.a, q1.a};
    K2 k1{q2.a, q0.b};
    K2 k2{q1.b, q2.b};
#endif
    t.sk[s][0] = k1.a; t.sk[s][1] = k1.b;
    t.sk[s][2] = k2.a; t.sk[s][3] = k2.b;
    k = kn;
  }
  return t;
}

__constant__ KeyTable g_keys = make_keys();

__device__ __forceinline__ uint32_t rng_bits32(uint32_t ka, uint32_t kb, uint32_t m) {
#if PARTITIONABLE
  K2 r = ctf(ka, kb, 0u, m);
  return r.a ^ r.b;
#else
  constexpr uint32_t H = (uint32_t)(kB * kN / 2);
  uint32_t p = (m < H) ? m : (m - H);
  K2 r = ctf(ka, kb, p, p + H);
  return (m < H) ? r.a : r.b;
#endif
}

__device__ __forceinline__ float bits_to_uniform(uint32_t bits) {
  // jax: bitcast(bits >> 9 | 0x3f800000) - 1.0
  return __uint_as_float((bits >> 9) | 0x3f800000u) - 1.0f;
}

// prep: betas + coalesced-permuted J (r12 layout, harness-verified).
// jpA float4 layout [c][slot][lane]: float4 idx = c*512 + slot*64 + l,
//   slot = (i&3)*2 + (f>>2), comp = f&3, where i = 4l + (i&3), j = 8c + f:
//   holds Jsym[4l + (i&3)][8c + (slot&1)*4 + comp].
// A load of (c, slot) across 64 lanes reads 64 contiguous float4 = 1 KB.
__global__ void prep_kernel(const float* __restrict__ gamma,
                            float* __restrict__ jpA,
                            float* __restrict__ betas) {
  int e = blockIdx.x * blockDim.x + threadIdx.x;   // 0..65535
  int i = e / kN, j = e % kN;
  float v = 0.0f;
  if (i < j) v = gamma[i * kN + j];
  else if (i > j) v = gamma[j * kN + i];
  int c = j >> 3, f = j & 7;
  int l = i >> 2, rl_ = i & 3;
  int slot = rl_ * 2 + (f >> 2);
  jpA[(((size_t)c * 512 + slot * 64 + l) << 2) + (f & 3)] = v;
  if (e < kSweeps) {
    double lo = log(0.1), hi = log(5.0);
    betas[e] = (float)exp(lo + (hi - lo) * (double)e / (double)(kSweeps - 1));
  }
}

// fp32 fma with fp16 spin operand converted in-op; spin word is the one
// scalar (SGPR) operand VOP3P allows. Exact: cvt(+-1.0h)=+-1.0f, then fp32
// fma -> bit-identical to fmaf(+-1.0f, J, acc). (r12 harness-verified.)
#define FMIX_LO_S(a, w, j)                                                    \
  asm("v_fma_mix_f32 %0, %1, %2, %0 op_sel:[0,0,0] op_sel_hi:[1,0,0]"         \
      : "+v"(a) : "s"(w), "v"(j))
#define FMIX_HI_S(a, w, j)                                                    \
  asm("v_fma_mix_f32 %0, %1, %2, %0 op_sel:[1,0,0] op_sel_hi:[1,0,0]"         \
      : "+v"(a) : "s"(w), "v"(j))

__global__ __launch_bounds__(512) void anneal_kernel(
    const float* __restrict__ thetas, const float* __restrict__ jpA,
    const float* __restrict__ betas, float* __restrict__ out) {
  // packed randoms w = ((b1>>9)<<1)|(b2>>31), one u32/site, dbuf: 32 KiB.
  // u1 = bitcast((w>>1)|0x3f800000)-1 (== bits_to_uniform(b1));
  // mask passes <=> (w&1)==0 <=> u2<0.5. (validated r1, r7-r13)
  __shared__ __align__(16) uint32_t sh_rand[2][kSamp * kN];

  const int tid = threadIdx.x;
  const int lane = tid & 63;
  const int wvid = tid >> 6;                 // wave 0..7 -> SIMD wvid%4
  const bool consumer = (wvid < 4);
  const int b0 = blockIdx.x * kSamp;

  if (consumer) {
    const int gbase = wvid * 4;              // this wave's 4 samples
    const int row0 = 4 * lane;               // this lane's rows (all samples)

    float4 th4[4];
    uint2 sreg[4];   // fp16 spins: .x = rows 4l,4l+1 (lo,hi); .y = 4l+2,4l+3
#pragma unroll
    for (int g = 0; g < 4; ++g)
      th4[g] = *(const float4*)&thetas[(b0 + gbase + g) * kN + row0];

    // s0 = where(bernoulli(k0, 0.5), 1, -1) ; bernoulli = uniform < 0.5
#pragma unroll
    for (int g = 0; g < 4; ++g) {
      uint32_t m0 = (uint32_t)((b0 + gbase + g) * kN + row0);
      uint32_t h[4];
#pragma unroll
      for (int r = 0; r < 4; ++r) {
        float u = bits_to_uniform(rng_bits32(g_keys.s0k[0], g_keys.s0k[1], m0 + r));
        h[r] = (u < 0.5f) ? 0x3C00u : 0xBC00u;
      }
      sreg[g].x = h[0] | (h[1] << 16);
      sreg[g].y = h[2] | (h[3] << 16);
    }
    __syncthreads();                         // rand buf0 ready (producers)

    // lane's J stream: float4 (c, slot) at jp4[c*512 + slot*64]
    const float4* __restrict__ jp4 = (const float4*)jpA + lane;

    // chunk c covers j = 8c..8c+7; spins for it live in lanes 2c, 2c+1:
    // f=0,1 -> w0=(x of lane 2c); f=2,3 -> w1=(y of 2c); f=4,5 -> w2=(x of
    // 2c+1); f=6,7 -> w3=(y of 2c+1). J: row r, f -> Jw[r*2+(f>>2)], comp
    // f&3. Chain (g,r) consumes f ascending -> exact j order. (r12-verified)
#define CONSUME_RL(c, Jw)                                                     \
  _Pragma("unroll")                                                           \
  for (int g = 0; g < 4; ++g) {                                               \
    const uint32_t w0 = (uint32_t)__builtin_amdgcn_readlane((int)sreg[g].x, 2*(c));     \
    const uint32_t w1 = (uint32_t)__builtin_amdgcn_readlane((int)sreg[g].y, 2*(c));     \
    const uint32_t w2 = (uint32_t)__builtin_amdgcn_readlane((int)sreg[g].x, 2*(c)+1);   \
    const uint32_t w3 = (uint32_t)__builtin_amdgcn_readlane((int)sreg[g].y, 2*(c)+1);   \
    _Pragma("unroll")                                                         \
    for (int r = 0; r < 4; ++r) {                                             \
      FMIX_LO_S(acc[4*g+r], w0, Jw[r*2+0].x);                                 \
      FMIX_HI_S(acc[4*g+r], w0, Jw[r*2+0].y);                                 \
      FMIX_LO_S(acc[4*g+r], w1, Jw[r*2+0].z);                                 \
      FMIX_HI_S(acc[4*g+r], w1, Jw[r*2+0].w);                                 \
      FMIX_LO_S(acc[4*g+r], w2, Jw[r*2+1].x);                                 \
      FMIX_HI_S(acc[4*g+r], w2, Jw[r*2+1].y);                                 \
      FMIX_LO_S(acc[4*g+r], w3, Jw[r*2+1].z);                                 \
      FMIX_HI_S(acc[4*g+r], w3, Jw[r*2+1].w);                                 \
    }                                                                         \
  }

    // rolled A/B pipeline over 32 chunks; J window prefetch one chunk ahead
#define MATVEC_RL(acc)                                                        \
  {                                                                           \
    float4 JA[8], JB[8];                                                      \
    _Pragma("unroll")                                                         \
    for (int r = 0; r < 8; ++r) JA[r] = jp4[r * 64];                          \
    _Pragma("unroll 1")                                                       \
    for (int k = 0; k < 16; ++k) {                                            \
      const int cA = 2 * k;                                                   \
      _Pragma("unroll")                                                       \
      for (int r = 0; r < 8; ++r) JB[r] = jp4[(cA + 1) * 512 + r * 64];       \
      CONSUME_RL(cA, JA)                                                      \
      if (k < 15) {                                                           \
        _Pragma("unroll")                                                     \
        for (int r = 0; r < 8; ++r) JA[r] = jp4[(cA + 2) * 512 + r * 64];     \
      }                                                                       \
      CONSUME_RL(cA + 1, JB)                                                  \
    }                                                                         \
  }

#pragma unroll 1
    for (int t = 0; t < kSweeps; ++t) {
      const float beta = betas[t];

      // randoms (produced last sweep / prologue): uint4 per sample
      uint4 wp[4];
#pragma unroll
      for (int g = 0; g < 4; ++g)
        wp[g] = *(const uint4*)&sh_rand[t & 1][(gbase + g) * kN + row0];

      float acc[16];
#pragma unroll
      for (int x = 0; x < 16; ++x) acc[x] = 0.0f;
      MATVEC_RL(acc)

#pragma unroll
      for (int g = 0; g < 4; ++g) {
        uint32_t px = sreg[g].x, py = sreg[g].y;
        float s0 = __uint_as_float(0x3F800000u | ((px << 16) & 0x80000000u));
        float s1 = __uint_as_float(0x3F800000u | (px & 0x80000000u));
        float s2 = __uint_as_float(0x3F800000u | ((py << 16) & 0x80000000u));
        float s3 = __uint_as_float(0x3F800000u | (py & 0x80000000u));
        float l0 = th4[g].x + acc[4 * g + 0];
        float l1 = th4[g].y + acc[4 * g + 1];
        float l2 = th4[g].z + acc[4 * g + 2];
        float l3 = th4[g].w + acc[4 * g + 3];
        float p0 = expf(-beta * (-2.0f * s0 * l0));   // (-2*s) exact pow2
        float p1 = expf(-beta * (-2.0f * s1 * l1));
        float p2 = expf(-beta * (-2.0f * s2 * l2));
        float p3 = expf(-beta * (-2.0f * s3 * l3));
        float u0 = __uint_as_float((wp[g].x >> 1) | 0x3f800000u) - 1.0f;
        float u1 = __uint_as_float((wp[g].y >> 1) | 0x3f800000u) - 1.0f;
        float u2 = __uint_as_float((wp[g].z >> 1) | 0x3f800000u) - 1.0f;
        float u3 = __uint_as_float((wp[g].w >> 1) | 0x3f800000u) - 1.0f;
        if ((u0 < p0) && ((wp[g].x & 1u) == 0u)) px ^= 0x8000u;
        if ((u1 < p1) && ((wp[g].y & 1u) == 0u)) px ^= 0x80000000u;
        if ((u2 < p2) && ((wp[g].z & 1u) == 0u)) py ^= 0x8000u;
        if ((u3 < p3) && ((wp[g].w & 1u) == 0u)) py ^= 0x80000000u;
        sreg[g].x = px; sreg[g].y = py;
      }
      __syncthreads();   // next rand buffer ready; waves stay chunk-aligned
    }

    // E_b = sum_i s_i*theta_i + 0.5 * sum_i s_i * (Jsym s)_i  (r12-verified)
    {
      float acc[16];
#pragma unroll
      for (int x = 0; x < 16; ++x) acc[x] = 0.0f;
      MATVEC_RL(acc)

#pragma unroll
      for (int g = 0; g < 4; ++g) {
        uint32_t px = sreg[g].x, py = sreg[g].y;
        float s0 = __uint_as_float(0x3F800000u | ((px << 16) & 0x80000000u));
        float s1 = __uint_as_float(0x3F800000u | (px & 0x80000000u));
        float s2 = __uint_as_float(0x3F800000u | ((py << 16) & 0x80000000u));
        float s3 = __uint_as_float(0x3F800000u | (py & 0x80000000u));
        float v0 = s0 * th4[g].x + 0.5f * (s0 * acc[4 * g + 0]);
        float v1 = s1 * th4[g].y + 0.5f * (s1 * acc[4 * g + 1]);
        float v2 = s2 * th4[g].z + 0.5f * (s2 * acc[4 * g + 2]);
        float v3 = s3 * th4[g].w + 0.5f * (s3 * acc[4 * g + 3]);
        float v = ((v0 + v1) + v2) + v3;     // fp32 regroup ok: bf16 compare
#pragma unroll
        for (int off = 32; off > 0; off >>= 1) v += __shfl_down(v, off);
        if (lane == 0) out[b0 + gbase + g] = v;
      }
    }
  } else {
    // ---------------- producer waves (4..7), r13-verified ----------------
    // store k covers sites pw*1024 + k*256 + lane*4 + 0..3: lane-contiguous
    // 16B -> conflict-free ds_write_b128.
    const int pw = wvid - 4;                 // 0..3
    {
      const uint32_t k1a = g_keys.sk[0][0], k1b = g_keys.sk[0][1];
      const uint32_t k2a = g_keys.sk[0][2], k2b = g_keys.sk[0][3];
#pragma unroll
      for (int k = 0; k < 4; ++k) {
        const uint32_t site = (uint32_t)(pw * 1024 + k * 256 + lane * 4);
        const uint32_t mb = (uint32_t)(b0 * kN) + site;
        uint32_t wv[4];
#pragma unroll
        for (int e = 0; e < 4; ++e) {
          uint32_t b1 = rng_bits32(k1a, k1b, mb + e);
          uint32_t b2 = rng_bits32(k2a, k2b, mb + e);
          wv[e] = ((b1 >> 9) << 1) | (b2 >> 31);
        }
        uint4 v; v.x = wv[0]; v.y = wv[1]; v.z = wv[2]; v.w = wv[3];
        *(uint4*)&sh_rand[0][site] = v;
      }
    }
    __syncthreads();

#pragma unroll 1
    for (int t = 0; t < kSweeps; ++t) {
      if (t + 1 < kSweeps) {
        const uint32_t k1a = g_keys.sk[t + 1][0], k1b = g_keys.sk[t + 1][1];
        const uint32_t k2a = g_keys.sk[t + 1][2], k2b = g_keys.sk[t + 1][3];
#pragma unroll
        for (int k = 0; k < 4; ++k) {
          const uint32_t site = (uint32_t)(pw * 1024 + k * 256 + lane * 4);
          const uint32_t mb = (uint32_t)(b0 * kN) + site;
          uint32_t wv[4];
#pragma unroll
          for (int e = 0; e < 4; ++e) {
            uint32_t b1 = rng_bits32(k1a, k1b, mb + e);
            uint32_t b2 = rng_bits32(k2a, k2b, mb + e);
            wv[e] = ((b1 >> 9) << 1) | (b2 >> 31);
          }
          uint4 v; v.x = wv[0]; v.y = wv[1]; v.z = wv[2]; v.w = wv[3];
          *(uint4*)&sh_rand[(t + 1) & 1][site] = v;
        }
      }
      __syncthreads();
    }
  }
}

}  // namespace

extern "C" void kernel_launch(void* const* d_in, const int* in_sizes, int n_in,
                              void* d_out, int out_size, void* d_ws, size_t ws_size,
                              hipStream_t stream) {
  const float* thetas = (const float*)d_in[0];   // [4096, 256]
  const float* gamma  = (const float*)d_in[1];   // [256, 256]
  char* ws = (char*)d_ws;
  float* jpA   = (float*)ws;                               // 256 KiB
  float* betas = (float*)(ws + (size_t)kN * kN * 4);       // 800 B

  hipLaunchKernelGGL(prep_kernel, dim3(kN), dim3(kN), 0, stream,
                     gamma, jpA, betas);
  hipLaunchKernelGGL(anneal_kernel, dim3(kBlocks), dim3(512), 0, stream,
                     thetas, jpA, betas, (float*)d_out);
}

// Round 15
// 2293.275 us; speedup vs baseline: 1.2267x; 1.2267x over previous
//
#include <hip/hip_runtime.h>
#include <stdint.h>
#include <math.h>

// Replicate jax.random threefry2x32 exactly (jax_threefry_partitionable=True).
#define PARTITIONABLE 1

namespace {

constexpr int kB = 4096;
constexpr int kN = 256;
constexpr int kSweeps = 200;
constexpr int kSamp = 16;                // samples per block
constexpr int kBlocks = kB / kSamp;      // 256 blocks of 512 threads -> 1/CU
// r13 frame + (4 rows, 4 samples) consumer + coalesced J:
//  waves 0-3: consumers — wave cw owns samples 4cw..4cw+3; lane holds rows
//    4l..4l+3. Spin-LDS reads halve vs r13 (512/CU/sweep): reads/CU =
//    sum(samples_per_wave)*32 and each sample is read by exactly one wave.
//    J layout = r12's coalesced jpA (1KB contiguous wave loads, verified).
//    No readlane / "s" constraints (r14's VGPR-demotion cause).
//  waves 4-7: producers — next sweep's threefry into LDS rand dbuf,
//    conflict-free 16B/lane stores (r13-verified).
// Wave w -> SIMD w%4: every SIMD runs 1 consumer + 1 producer.

struct K2 { uint32_t a, b; };

__host__ __device__ constexpr uint32_t crotl(uint32_t x, int d) {
  return (x << d) | (x >> (32 - d));
}

// Threefry-2x32, 20 rounds, exactly as jax/_src/prng.py
__host__ __device__ constexpr K2 ctf(uint32_t k0, uint32_t k1, uint32_t c0, uint32_t c1) {
  uint32_t ks0 = k0, ks1 = k1, ks2 = k0 ^ k1 ^ 0x1BD11BDAu;
  uint32_t x0 = c0 + ks0, x1 = c1 + ks1;
  const int r0[4] = {13, 15, 26, 6};
  const int r1[4] = {17, 29, 16, 24};
  for (int i = 0; i < 4; ++i) { x0 += x1; x1 = crotl(x1, r0[i]); x1 ^= x0; }
  x0 += ks1; x1 += ks2 + 1u;
  for (int i = 0; i < 4; ++i) { x0 += x1; x1 = crotl(x1, r1[i]); x1 ^= x0; }
  x0 += ks2; x1 += ks0 + 2u;
  for (int i = 0; i < 4; ++i) { x0 += x1; x1 = crotl(x1, r0[i]); x1 ^= x0; }
  x0 += ks0; x1 += ks1 + 3u;
  for (int i = 0; i < 4; ++i) { x0 += x1; x1 = crotl(x1, r1[i]); x1 ^= x0; }
  x0 += ks1; x1 += ks2 + 4u;
  for (int i = 0; i < 4; ++i) { x0 += x1; x1 = crotl(x1, r0[i]); x1 ^= x0; }
  x0 += ks2; x1 += ks0 + 5u;
  return K2{x0, x1};
}

struct KeyTable {
  uint32_t s0k[2];               // key for initial spins (k0)
  uint32_t sk[kSweeps][4];       // per sweep: k1a,k1b (accept), k2a,k2b (mask)
};

constexpr KeyTable make_keys() {
  KeyTable t{};
  K2 root{0u, 42u};              // jax.random.key(42) -> (hi=0, lo=42)
#if PARTITIONABLE
  K2 k0 = ctf(root.a, root.b, 0u, 0u);
  K2 kl = ctf(root.a, root.b, 0u, 1u);
#else
  K2 p0 = ctf(root.a, root.b, 0u, 2u);
  K2 p1 = ctf(root.a, root.b, 1u, 3u);
  K2 k0{p0.a, p1.a};
  K2 kl{p0.b, p1.b};
#endif
  t.s0k[0] = k0.a; t.s0k[1] = k0.b;
  K2 k = kl;
  for (int s = 0; s < kSweeps; ++s) {
#if PARTITIONABLE
    K2 kn = ctf(k.a, k.b, 0u, 0u);
    K2 k1 = ctf(k.a, k.b, 0u, 1u);
    K2 k2 = ctf(k.a, k.b, 0u, 2u);
#else
    K2 q0 = ctf(k.a, k.b, 0u, 3u);
    K2 q1 = ctf(k.a, k.b, 1u, 4u);
    K2 q2 = ctf(k.a, k.b, 2u, 5u);
    K2 kn{q0.a, q1.a};
    K2 k1{q2.a, q0.b};
    K2 k2{q1.b, q2.b};
#endif
    t.sk[s][0] = k1.a; t.sk[s][1] = k1.b;
    t.sk[s][2] = k2.a; t.sk[s][3] = k2.b;
    k = kn;
  }
  return t;
}

__constant__ KeyTable g_keys = make_keys();

__device__ __forceinline__ uint32_t rng_bits32(uint32_t ka, uint32_t kb, uint32_t m) {
#if PARTITIONABLE
  K2 r = ctf(ka, kb, 0u, m);
  return r.a ^ r.b;
#else
  constexpr uint32_t H = (uint32_t)(kB * kN / 2);
  uint32_t p = (m < H) ? m : (m - H);
  K2 r = ctf(ka, kb, p, p + H);
  return (m < H) ? r.a : r.b;
#endif
}

__device__ __forceinline__ float bits_to_uniform(uint32_t bits) {
  // jax: bitcast(bits >> 9 | 0x3f800000) - 1.0
  return __uint_as_float((bits >> 9) | 0x3f800000u) - 1.0f;
}

// prep: betas + coalesced-permuted J (r12 layout, harness-verified).
// jpA float4 layout [c][slot][lane]: float4 idx = c*512 + slot*64 + l,
//   slot = (i&3)*2 + (f>>2), comp = f&3, where i = 4l + (i&3), j = 8c + f:
//   holds Jsym[4l + (i&3)][8c + (slot&1)*4 + comp].
// A load of (c, slot) across 64 lanes reads 64 contiguous float4 = 1 KB.
__global__ void prep_kernel(const float* __restrict__ gamma,
                            float* __restrict__ jpA,
                            float* __restrict__ betas) {
  int e = blockIdx.x * blockDim.x + threadIdx.x;   // 0..65535
  int i = e / kN, j = e % kN;
  float v = 0.0f;
  if (i < j) v = gamma[i * kN + j];
  else if (i > j) v = gamma[j * kN + i];
  int c = j >> 3, f = j & 7;
  int l = i >> 2, rl_ = i & 3;
  int slot = rl_ * 2 + (f >> 2);
  jpA[(((size_t)c * 512 + slot * 64 + l) << 2) + (f & 3)] = v;
  if (e < kSweeps) {
    double lo = log(0.1), hi = log(5.0);
    betas[e] = (float)exp(lo + (hi - lo) * (double)e / (double)(kSweeps - 1));
  }
}

// One VALU op per element: f32 fma with the f16 spin operand converted in-op.
// Conversion of +-1.0h to f32 is exact, then fp32 fma -> bit-identical to
// fmaf(+-1.0f, J, acc). op_sel picks lo/hi half of the packed u32.
#define FMIX_LO(a, w, j)                                                      \
  asm("v_fma_mix_f32 %0, %1, %2, %0 op_sel:[0,0,0] op_sel_hi:[1,0,0]"         \
      : "+v"(a) : "v"(w), "v"(j))
#define FMIX_HI(a, w, j)                                                      \
  asm("v_fma_mix_f32 %0, %1, %2, %0 op_sel:[1,0,0] op_sel_hi:[1,0,0]"         \
      : "+v"(a) : "v"(w), "v"(j))

__global__ __launch_bounds__(512) void anneal_kernel(
    const float* __restrict__ thetas, const float* __restrict__ jpA,
    const float* __restrict__ betas, float* __restrict__ out) {
  // fp16 spins (+1.0h=0x3C00, -1.0h=0xBC00), [buf][g][row], dbuf: 16 KiB
  __shared__ __align__(16) unsigned short sh_h[2][kSamp][kN];
  // packed randoms w = ((b1>>9)<<1)|(b2>>31), one u32/site, dbuf: 32 KiB.
  // u1 = bitcast((w>>1)|0x3f800000)-1 (== bits_to_uniform(b1));
  // mask passes <=> (w&1)==0 <=> u2<0.5. (validated r1, r7-r14)
  __shared__ __align__(16) uint32_t sh_rand[2][kSamp * kN];

  const int tid = threadIdx.x;
  const int lane = tid & 63;
  const int wvid = tid >> 6;                 // wave 0..7 -> SIMD wvid%4
  const bool consumer = (wvid < 4);
  const int b0 = blockIdx.x * kSamp;

  int cur = 0;

  if (consumer) {
    const int gbase = wvid * 4;              // this wave's 4 samples
    const int row0 = 4 * lane;               // this lane's rows 4l..4l+3

    float4 th4[4];
    uint2 sreg[4];   // fp16 spins: .x = rows 4l,4l+1 (lo,hi); .y = 4l+2,4l+3
#pragma unroll
    for (int g = 0; g < 4; ++g)
      th4[g] = *(const float4*)&thetas[(b0 + gbase + g) * kN + row0];

    // s0 = where(bernoulli(k0, 0.5), 1, -1) ; bernoulli = uniform < 0.5
#pragma unroll
    for (int g = 0; g < 4; ++g) {
      uint32_t m0 = (uint32_t)((b0 + gbase + g) * kN + row0);
      uint32_t h[4];
#pragma unroll
      for (int r = 0; r < 4; ++r) {
        float u = bits_to_uniform(rng_bits32(g_keys.s0k[0], g_keys.s0k[1], m0 + r));
        h[r] = (u < 0.5f) ? 0x3C00u : 0xBC00u;
      }
      sreg[g].x = h[0] | (h[1] << 16);
      sreg[g].y = h[2] | (h[3] << 16);
      *(uint2*)&sh_h[0][gbase + g][row0] = sreg[g];
    }
    __syncthreads();                         // spins + rand buf0 ready

    // lane's coalesced J stream: float4 (c, slot) at jp4[c*512 + slot*64]
    const float4* __restrict__ jp4 = (const float4*)jpA + lane;

    // spins of chunk c (j=8c..8c+7) for sample g: one broadcast uint4
#define LDSPIN4(g, c) (*(const uint4*)&sh_h[cur][gbase + (g)][(c) * 8])
    // consume chunk for 4 samples x 4 rows: 128 fma_mix, f (=j) ascending
    // per (g,rl) chain. J: row rl, f -> Jw[rl*2+(f>>2)] comp f&3 (jpA def).
#define CONSUME4(W, Jw)                                                       \
  _Pragma("unroll")                                                           \
  for (int g = 0; g < 4; ++g) {                                               \
    _Pragma("unroll")                                                         \
    for (int rl = 0; rl < 4; ++rl) {                                          \
      FMIX_LO(acc[4*g+rl], W[g].x, Jw[rl*2+0].x);                             \
      FMIX_HI(acc[4*g+rl], W[g].x, Jw[rl*2+0].y);                             \
      FMIX_LO(acc[4*g+rl], W[g].y, Jw[rl*2+0].z);                             \
      FMIX_HI(acc[4*g+rl], W[g].y, Jw[rl*2+0].w);                             \
      FMIX_LO(acc[4*g+rl], W[g].z, Jw[rl*2+1].x);                             \
      FMIX_HI(acc[4*g+rl], W[g].z, Jw[rl*2+1].y);                             \
      FMIX_LO(acc[4*g+rl], W[g].w, Jw[rl*2+1].z);                             \
      FMIX_HI(acc[4*g+rl], W[g].w, Jw[rl*2+1].w);                             \
    }                                                                         \
  }
    // rolled 15-iter A/B pipeline (r11/r13-proven register shape)
#define MATVEC4(acc)                                                          \
  {                                                                           \
    uint4 A[4], Bw[4];                                                        \
    float4 JA[8], JB[8];                                                      \
    _Pragma("unroll")                                                         \
    for (int g = 0; g < 4; ++g) A[g] = LDSPIN4(g, 0);                         \
    _Pragma("unroll")                                                         \
    for (int r = 0; r < 8; ++r) JA[r] = jp4[r * 64];                          \
    _Pragma("unroll 1")                                                       \
    for (int k = 0; k < 15; ++k) {                                            \
      const int c = 2 * k;                                                    \
      _Pragma("unroll")                                                       \
      for (int g = 0; g < 4; ++g) Bw[g] = LDSPIN4(g, c + 1);                  \
      _Pragma("unroll")                                                       \
      for (int r = 0; r < 8; ++r) JB[r] = jp4[(c + 1) * 512 + r * 64];        \
      CONSUME4(A, JA)                                                         \
      _Pragma("unroll")                                                       \
      for (int g = 0; g < 4; ++g) A[g] = LDSPIN4(g, c + 2);                   \
      _Pragma("unroll")                                                       \
      for (int r = 0; r < 8; ++r) JA[r] = jp4[(c + 2) * 512 + r * 64];        \
      CONSUME4(Bw, JB)                                                        \
    }                                                                         \
    _Pragma("unroll")                                                         \
    for (int g = 0; g < 4; ++g) Bw[g] = LDSPIN4(g, 31);                       \
    _Pragma("unroll")                                                         \
    for (int r = 0; r < 8; ++r) JB[r] = jp4[31 * 512 + r * 64];               \
    CONSUME4(A, JA)                                                           \
    CONSUME4(Bw, JB)                                                          \
  }

#pragma unroll 1
    for (int t = 0; t < kSweeps; ++t) {
      const float beta = betas[t];

      // randoms (produced last sweep / prologue): uint4 per sample
      uint4 wp[4];
#pragma unroll
      for (int g = 0; g < 4; ++g)
        wp[g] = *(const uint4*)&sh_rand[t & 1][(gbase + g) * kN + row0];

      float acc[16];
#pragma unroll
      for (int x = 0; x < 16; ++x) acc[x] = 0.0f;
      MATVEC4(acc)

#pragma unroll
      for (int g = 0; g < 4; ++g) {
        uint32_t px = sreg[g].x, py = sreg[g].y;
        float s0 = __uint_as_float(0x3F800000u | ((px << 16) & 0x80000000u));
        float s1 = __uint_as_float(0x3F800000u | (px & 0x80000000u));
        float s2 = __uint_as_float(0x3F800000u | ((py << 16) & 0x80000000u));
        float s3 = __uint_as_float(0x3F800000u | (py & 0x80000000u));
        float l0 = th4[g].x + acc[4 * g + 0];
        float l1 = th4[g].y + acc[4 * g + 1];
        float l2 = th4[g].z + acc[4 * g + 2];
        float l3 = th4[g].w + acc[4 * g + 3];
        float p0 = expf(-beta * (-2.0f * s0 * l0));   // (-2*s) exact pow2
        float p1 = expf(-beta * (-2.0f * s1 * l1));
        float p2 = expf(-beta * (-2.0f * s2 * l2));
        float p3 = expf(-beta * (-2.0f * s3 * l3));
        float u0 = __uint_as_float((wp[g].x >> 1) | 0x3f800000u) - 1.0f;
        float u1 = __uint_as_float((wp[g].y >> 1) | 0x3f800000u) - 1.0f;
        float u2 = __uint_as_float((wp[g].z >> 1) | 0x3f800000u) - 1.0f;
        float u3 = __uint_as_float((wp[g].w >> 1) | 0x3f800000u) - 1.0f;
        if ((u0 < p0) && ((wp[g].x & 1u) == 0u)) px ^= 0x8000u;
        if ((u1 < p1) && ((wp[g].y & 1u) == 0u)) px ^= 0x80000000u;
        if ((u2 < p2) && ((wp[g].z & 1u) == 0u)) py ^= 0x8000u;
        if ((u3 < p3) && ((wp[g].w & 1u) == 0u)) py ^= 0x80000000u;
        sreg[g].x = px; sreg[g].y = py;
        *(uint2*)&sh_h[cur ^ 1][gbase + g][row0] = sreg[g];
      }
      __syncthreads();   // spins(next) + rand(t+1) ready
      cur ^= 1;
    }

    // E_b = sum_i s_i*theta_i + 0.5 * sum_i s_i * (Jsym s)_i  (r12/r14 tree)
    {
      float acc[16];
#pragma unroll
      for (int x = 0; x < 16; ++x) acc[x] = 0.0f;
      MATVEC4(acc)

#pragma unroll
      for (int g = 0; g < 4; ++g) {
        uint32_t px = sreg[g].x, py = sreg[g].y;
        float s0 = __uint_as_float(0x3F800000u | ((px << 16) & 0x80000000u));
        float s1 = __uint_as_float(0x3F800000u | (px & 0x80000000u));
        float s2 = __uint_as_float(0x3F800000u | ((py << 16) & 0x80000000u));
        float s3 = __uint_as_float(0x3F800000u | (py & 0x80000000u));
        float v0 = s0 * th4[g].x + 0.5f * (s0 * acc[4 * g + 0]);
        float v1 = s1 * th4[g].y + 0.5f * (s1 * acc[4 * g + 1]);
        float v2 = s2 * th4[g].z + 0.5f * (s2 * acc[4 * g + 2]);
        float v3 = s3 * th4[g].w + 0.5f * (s3 * acc[4 * g + 3]);
        float v = ((v0 + v1) + v2) + v3;     // fp32 regroup ok: bf16 compare
#pragma unroll
        for (int off = 32; off > 0; off >>= 1) v += __shfl_down(v, off);
        if (lane == 0) out[b0 + gbase + g] = v;
      }
    }
  } else {
    // ---------------- producer waves (4..7), r13-verified ----------------
    // store k covers sites pw*1024 + k*256 + lane*4 + 0..3: lane-contiguous
    // 16B -> conflict-free ds_write_b128.
    const int pw = wvid - 4;                 // 0..3
    {
      const uint32_t k1a = g_keys.sk[0][0], k1b = g_keys.sk[0][1];
      const uint32_t k2a = g_keys.sk[0][2], k2b = g_keys.sk[0][3];
#pragma unroll
      for (int k = 0; k < 4; ++k) {
        const uint32_t site = (uint32_t)(pw * 1024 + k * 256 + lane * 4);
        const uint32_t mb = (uint32_t)(b0 * kN) + site;
        uint32_t wv[4];
#pragma unroll
        for (int e = 0; e < 4; ++e) {
          uint32_t b1 = rng_bits32(k1a, k1b, mb + e);
          uint32_t b2 = rng_bits32(k2a, k2b, mb + e);
          wv[e] = ((b1 >> 9) << 1) | (b2 >> 31);
        }
        uint4 v; v.x = wv[0]; v.y = wv[1]; v.z = wv[2]; v.w = wv[3];
        *(uint4*)&sh_rand[0][site] = v;
      }
    }
    __syncthreads();

#pragma unroll 1
    for (int t = 0; t < kSweeps; ++t) {
      if (t + 1 < kSweeps) {
        const uint32_t k1a = g_keys.sk[t + 1][0], k1b = g_keys.sk[t + 1][1];
        const uint32_t k2a = g_keys.sk[t + 1][2], k2b = g_keys.sk[t + 1][3];
#pragma unroll
        for (int k = 0; k < 4; ++k) {
          const uint32_t site = (uint32_t)(pw * 1024 + k * 256 + lane * 4);
          const uint32_t mb = (uint32_t)(b0 * kN) + site;
          uint32_t wv[4];
#pragma unroll
          for (int e = 0; e < 4; ++e) {
            uint32_t b1 = rng_bits32(k1a, k1b, mb + e);
            uint32_t b2 = rng_bits32(k2a, k2b, mb + e);
            wv[e] = ((b1 >> 9) << 1) | (b2 >> 31);
          }
          uint4 v; v.x = wv[0]; v.y = wv[1]; v.z = wv[2]; v.w = wv[3];
          *(uint4*)&sh_rand[(t + 1) & 1][site] = v;
        }
      }
      __syncthreads();
    }
  }
}

}  // namespace

extern "C" void kernel_launch(void* const* d_in, const int* in_sizes, int n_in,
                              void* d_out, int out_size, void* d_ws, size_t ws_size,
                              hipStream_t stream) {
  const float* thetas = (const float*)d_in[0];   // [4096, 256]
  const float* gamma  = (const float*)d_in[1];   // [256, 256]
  char* ws = (char*)d_ws;
  float* jpA   = (float*)ws;                               // 256 KiB
  float* betas = (float*)(ws + (size_t)kN * kN * 4);       // 800 B

  hipLaunchKernelGGL(prep_kernel, dim3(kN), dim3(kN), 0, stream,
                     gamma, jpA, betas);
  hipLaunchKernelGGL(anneal_kernel, dim3(kBlocks), dim3(512), 0, stream,
                     thetas, jpA, betas, (float*)d_out);
}